// Round 4
// baseline (351.935 us; speedup 1.0000x reference)
//
#include <hip/hip_runtime.h>
#include <stdint.h>

#define BLOCK 128

struct KeySet {
  uint32_t k0L[6], k1L[6], k2L[6], k0R[6], k1R[6], k2R[6];
};

// Threefry-2x32 host copy for the key chain (split) — bit-exact with device.
__host__ inline void tf2x32(uint32_t k0, uint32_t k1, uint32_t x0, uint32_t x1,
                            uint32_t& o0, uint32_t& o1) {
  const uint32_t k2 = k0 ^ k1 ^ 0x1BD11BDAu;
  x0 += k0; x1 += k1;
#define TFR(r) { x0 += x1; x1 = (x1 << (r)) | (x1 >> (32 - (r))); x1 ^= x0; }
  TFR(13) TFR(15) TFR(26) TFR(6)
  x0 += k1; x1 += k2 + 1u;
  TFR(17) TFR(29) TFR(16) TFR(24)
  x0 += k2; x1 += k0 + 2u;
  TFR(13) TFR(15) TFR(26) TFR(6)
  x0 += k0; x1 += k1 + 3u;
  TFR(17) TFR(29) TFR(16) TFR(24)
  x0 += k1; x1 += k2 + 4u;
  TFR(13) TFR(15) TFR(26) TFR(6)
  x0 += k2; x1 += k0 + 5u;
#undef TFR
  o0 = x0; o1 = x1;
}

// Gumbel-softmax weight factor: e^g = 1/(-ln u) ∝ 1/(-log2 u) (ln2 cancels
// in num/den). Weights from LDS are w'_c = exp(logit_c)*2^-24.
__device__ __forceinline__ float wgt(uint32_t bits) {
  const float tiny = 1.17549435e-38f;
  float f = __uint_as_float((bits >> 9) | 0x3f800000u) - 1.0f;
  float u = fmaxf(f, tiny);                 // JAX uniform in [tiny, 1)
  float v = __builtin_amdgcn_logf(u);       // log2(u)
  return __builtin_amdgcn_rcpf(-v);         // neg folds as input modifier
}

__device__ __forceinline__ float expT(float x) {  // sum_{k=0..12} x^k/k!
  float r = 2.0876756987868099e-9f;               // 1/12!
  r = fmaf(r, x, 2.5052108385441719e-8f);
  r = fmaf(r, x, 2.7557319223985893e-7f);
  r = fmaf(r, x, 2.7557319223985888e-6f);
  r = fmaf(r, x, 2.4801587301587302e-5f);
  r = fmaf(r, x, 1.9841269841269841e-4f);
  r = fmaf(r, x, 1.3888888888888889e-3f);
  r = fmaf(r, x, 8.3333333333333332e-3f);
  r = fmaf(r, x, 4.1666666666666664e-2f);
  r = fmaf(r, x, 1.6666666666666666e-1f);
  r = fmaf(r, x, 0.5f);
  r = fmaf(r, x, 1.0f);
  r = fmaf(r, x, 1.0f);
  return r;
}

__device__ __forceinline__ float lnT(float y) {   // k=16..1: r = 1/k - z*r; z*r
  const float inv[15] = {1.0f/15.0f, 1.0f/14.0f, 1.0f/13.0f, 1.0f/12.0f,
                         1.0f/11.0f, 0.1f, 1.0f/9.0f, 0.125f, 1.0f/7.0f, 1.0f/6.0f,
                         0.2f, 0.25f, 1.0f/3.0f, 0.5f, 1.0f};
  float z = y - 1.0f;
  float r = 1.0f/16.0f;                     // first iteration folded
#pragma unroll
  for (int i = 0; i < 15; ++i) r = fmaf(-z, r, inv[i]);
  return z * r;
}

// One node: 2C independent threefry chains (L side = 0..C-1, R = C..2C-1)
// explicitly interleaved so the scheduler always has 2C independent ops at
// every step of the serial add/rotl/xor dependency chain (World-DEP fix).
// All array indices are compile-time (full unroll) -> registers, not scratch.
template<int C, bool HP>
__device__ __forceinline__ float node_eval(
    const float* __restrict__ w8,     // LDS [2][8] weights for this node
    const uint32_t K0[2], const uint32_t K1[2], const uint32_t K2[2],
    uint32_t xL, uint32_t xR,         // counter bases (k1 pre-added)
    float4 xv, float pl, float pr) {
  constexpr int N = 2 * C;
  uint32_t a0[N], a1[N];
#pragma unroll
  for (int i = 0; i < N; ++i) {
    const int s = (i < C) ? 0 : 1;
    a0[i] = K0[s];
    a1[i] = ((i < C) ? xL : xR) + (uint32_t)(i < C ? i : i - C);
  }
#define HALF(r) \
  _Pragma("unroll") for (int i = 0; i < N; ++i) { \
    a0[i] += a1[i]; \
    a1[i] = __builtin_rotateleft32(a1[i], (r)); \
    a1[i] ^= a0[i]; }
#define INJ(A, B, add) \
  _Pragma("unroll") for (int i = 0; i < N; ++i) { \
    const int s = (i < C) ? 0 : 1; \
    a0[i] += A[s]; a1[i] += B[s] + (add); }
  HALF(13) HALF(15) HALF(26) HALF(6)
  INJ(K1, K2, 1u)
  HALF(17) HALF(29) HALF(16) HALF(24)
  INJ(K2, K0, 2u)
  HALF(13) HALF(15) HALF(26) HALF(6)
  INJ(K0, K1, 3u)
  HALF(17) HALF(29) HALF(16) HALF(24)
  INJ(K1, K2, 4u)
  HALF(13) HALF(15) HALF(26) HALF(6)
#undef HALF
#undef INJ
  float wv[N];
#pragma unroll
  for (int i = 0; i < N; ++i) {
    const int s = (i < C) ? 0 : 1;
    wv[i] = wgt((a0[i] + K2[s]) ^ (a1[i] + K0[s] + 5u));
  }
  // Accumulation order identical to R3: c ascending, den then num.
  float e = w8[0] * wv[0];
  float denL = e, numL = e;
  e = w8[1] * wv[1]; denL += e; numL = fmaf(e, xv.x, numL);
  e = w8[2] * wv[2]; denL += e; numL = fmaf(e, xv.y, numL);
  e = w8[3] * wv[3]; denL += e; numL = fmaf(e, xv.z, numL);
  e = w8[4] * wv[4]; denL += e; numL = fmaf(e, xv.w, numL);
  if constexpr (C == 6) { e = w8[5] * wv[5]; denL += e; numL = fmaf(e, pl, numL); }
  e = w8[8] * wv[C];
  float denR = e, numR = e;
  e = w8[9]  * wv[C + 1]; denR += e; numR = fmaf(e, xv.x, numR);
  e = w8[10] * wv[C + 2]; denR += e; numR = fmaf(e, xv.y, numR);
  e = w8[11] * wv[C + 3]; denR += e; numR = fmaf(e, xv.z, numR);
  e = w8[12] * wv[C + 4]; denR += e; numR = fmaf(e, xv.w, numR);
  if constexpr (C == 6) { e = w8[13] * wv[N - 1]; denR += e; numR = fmaf(e, pr, numR); }
  float ex = numL * __builtin_amdgcn_rcpf(denL);
  float ey = numR * __builtin_amdgcn_rcpf(denR);
  ex = __builtin_amdgcn_fmed3f(ex, -5.0f, 5.0f);  // CLAMP
  ey = fmaxf(ey, 1e-30f);                          // LN_EPS
  return expT(ex) + lnT(ey);
}

// One tree level. wl = LDS weights [node][side][8] for this block's t.
// pv = &pvs[tid]; prev row j at pv[j*BLOCK]. In-place write is hazard-free:
// iteration n reads rows 2n,2n+1 before writing row n (n <= 2n).
template<int C, bool HP>
__device__ __forceinline__ void level_run(int nodes, const float* __restrict__ wl,
    const uint32_t* __restrict__ kk,   // {k0L,k1L,k2L,k0R,k1R,k2R}
    uint32_t bt, uint32_t stride, float4 xv, float* __restrict__ pv) {
  const uint32_t K0[2] = {kk[0], kk[3]};
  const uint32_t K1[2] = {kk[1], kk[4]};
  const uint32_t K2[2] = {kk[2], kk[5]};
  const uint32_t xbL = bt * stride + kk[1];
  const uint32_t xbR = bt * stride + kk[4];
  for (int n = 0; n < nodes; ++n) {
    float pl = 0.0f, pr = 0.0f;
    if constexpr (HP) {
      pl = pv[(2 * n) * BLOCK];          // hoisted: LDS latency hides under rounds
      pr = pv[(2 * n + 1) * BLOCK];
    }
    float r = node_eval<C, HP>(wl + n * 16, K0, K1, K2,
                               xbL + (uint32_t)(n * C), xbR + (uint32_t)(n * C),
                               xv, pl, pr);
    pv[n * BLOCK] = r;
  }
}

// Stage one level's logits into padded weight layout [node][side][8]:
// w' = exp2(logit*log2e - 24)  (2^-24 prevents num overflow when rcp
// weights (<=5.8e6) meet prev ~ 1e33).
template<int C>
__device__ __forceinline__ void stage(const float* __restrict__ g, float* __restrict__ ws,
                                      int t, int N, int woff, int tid) {
  const int total = N * C * 2;
  const float* src = g + t * total;
  for (int i = tid; i < total; i += BLOCK) {
    int n = i / (2 * C);
    int rem = i - n * 2 * C;
    int c = rem >> 1, s = rem & 1;
    ws[woff + n * 16 + s * 8 + c] =
        __builtin_amdgcn_exp2f(fmaf(src[i], 1.4426950408889634f, -24.0f));
  }
}

__global__ __launch_bounds__(BLOCK, 4) void eml_kernel(
    const float* __restrict__ x,
    const float* __restrict__ g0, const float* __restrict__ g1,
    const float* __restrict__ g2, const float* __restrict__ g3,
    const float* __restrict__ g4, const float* __restrict__ g5,
    float* __restrict__ out, KeySet ks) {
  __shared__ float wz[1008];            // padded weights, levels concatenated
  __shared__ float pvs[32 * BLOCK];     // prev rows [node][tid] — conflict-free
  const int tid = threadIdx.x;
  const int t = blockIdx.x & 127;
  const int chunk = blockIdx.x >> 7;    // 0..15

  stage<5>(g0, wz, t, 32,   0, tid);
  stage<6>(g1, wz, t, 16, 512, tid);
  stage<6>(g2, wz, t,  8, 768, tid);
  stage<6>(g3, wz, t,  4, 896, tid);
  stage<6>(g4, wz, t,  2, 960, tid);
  stage<6>(g5, wz, t,  1, 992, tid);
  __syncthreads();

  const int b = chunk * BLOCK + tid;                 // coalesced x reads
  const uint32_t bt = (uint32_t)(b * 128 + t);       // flat (b,t) index
  const float4 xv = reinterpret_cast<const float4*>(x)[b];
  float* pv = &pvs[tid];

  uint32_t kk[6][6];
#pragma unroll
  for (int l = 0; l < 6; ++l) {
    kk[l][0] = ks.k0L[l]; kk[l][1] = ks.k1L[l]; kk[l][2] = ks.k2L[l];
    kk[l][3] = ks.k0R[l]; kk[l][4] = ks.k1R[l]; kk[l][5] = ks.k2R[l];
  }

  level_run<5, false>(32, wz,       kk[0], bt, 160u, xv, pv);
  level_run<6, true >(16, wz + 512, kk[1], bt,  96u, xv, pv);
  level_run<6, true >( 8, wz + 768, kk[2], bt,  48u, xv, pv);
  level_run<6, true >( 4, wz + 896, kk[3], bt,  24u, xv, pv);
  level_run<6, true >( 2, wz + 960, kk[4], bt,  12u, xv, pv);
  level_run<6, true >( 1, wz + 992, kk[5], bt,   6u, xv, pv);

  out[bt] = pvs[tid];
}

extern "C" void kernel_launch(void* const* d_in, const int* in_sizes, int n_in,
                              void* d_out, int out_size, void* d_ws, size_t ws_size,
                              hipStream_t stream) {
  const float* x  = (const float*)d_in[0];
  const float* g0 = (const float*)d_in[1];
  const float* g1 = (const float*)d_in[2];
  const float* g2 = (const float*)d_in[3];
  const float* g3 = (const float*)d_in[4];
  const float* g4 = (const float*)d_in[5];
  const float* g5 = (const float*)d_in[6];
  float* out = (float*)d_out;

  // Key chain: key(42) = (0,42); per level split(key,3) fold-like:
  // key' = tf(key,(0,0)), kL = tf(key,(0,1)), kR = tf(key,(0,2)).
  KeySet ks;
  uint32_t K0 = 0u, K1 = 42u;
  for (int l = 0; l < 6; ++l) {
    uint32_t n0, n1, a0, a1, c0, c1;
    tf2x32(K0, K1, 0u, 0u, n0, n1);
    tf2x32(K0, K1, 0u, 1u, a0, a1);
    tf2x32(K0, K1, 0u, 2u, c0, c1);
    ks.k0L[l] = a0; ks.k1L[l] = a1; ks.k2L[l] = a0 ^ a1 ^ 0x1BD11BDAu;
    ks.k0R[l] = c0; ks.k1R[l] = c1; ks.k2R[l] = c0 ^ c1 ^ 0x1BD11BDAu;
    K0 = n0; K1 = n1;
  }

  eml_kernel<<<dim3(2048), dim3(BLOCK), 0, stream>>>(x, g0, g1, g2, g3, g4, g5, out, ks);
}